// Round 1
// baseline (679.268 us; speedup 1.0000x reference)
//
#include <hip/hip_runtime.h>
#include <hip/hip_bf16.h>
#include <cstdint>
#include <cstddef>

#define NB 8
#define NS 1024
#define NH 1024
#define ND 64

__device__ __forceinline__ unsigned short f2bf(float x) {
    unsigned int u = __float_as_uint(x);
    unsigned int r = (u + 0x7fffu + ((u >> 16) & 1u)) >> 16;
    return (unsigned short)r;
}
__device__ __forceinline__ float bflo(unsigned int pr) { return __uint_as_float(pr << 16); }
__device__ __forceinline__ float bfhi(unsigned int pr) { return __uint_as_float(pr & 0xffff0000u); }

// ---------------------------------------------------------------------------
// Projection: dst[p] = A @ W + bias, A:[8192,1024] W:[1024,64]
// grid (128, 3), block 256. Tile: 64 rows x 64 cols, per-thread 2x8.
// ---------------------------------------------------------------------------
__global__ __launch_bounds__(256, 2) void proj_kernel(
    const float* __restrict__ qin, const float* __restrict__ kin, const float* __restrict__ vin,
    const float* __restrict__ Wq, const float* __restrict__ bq,
    const float* __restrict__ Wk, const float* __restrict__ bk,
    const float* __restrict__ Wv, const float* __restrict__ bv,
    float* __restrict__ ws)
{
    __shared__ float At[64][66];   // A-tile transposed: At[kk][row]

    const int p = blockIdx.y;
    const float* A    = (p == 0) ? qin : (p == 1) ? kin : vin;
    const float* W    = (p == 0) ? Wq  : (p == 1) ? Wk  : Wv;
    const float* bias = (p == 0) ? bq  : (p == 1) ? bk  : bv;
    float* dst = ws + (size_t)p * (NB * NS * ND);

    const int t  = threadIdx.x;
    const int r0 = blockIdx.x * 64;
    const int tr = t >> 3;   // 0..31 -> rows 2tr, 2tr+1
    const int tc = t & 7;    // cols 8tc .. 8tc+7

    float acc0[8], acc1[8];
    #pragma unroll
    for (int j = 0; j < 8; ++j) { acc0[j] = 0.f; acc1[j] = 0.f; }

    const int sr = t >> 4;          // 0..15
    const int sc = (t & 15) * 4;    // 0..60

    for (int h0 = 0; h0 < NH; h0 += 64) {
        // stage A[r0..r0+63][h0..h0+63] transposed
        #pragma unroll
        for (int pp = 0; pp < 4; ++pp) {
            int r = sr + 16 * pp;
            float4 a4 = *(const float4*)&A[(size_t)(r0 + r) * NH + h0 + sc];
            At[sc + 0][r] = a4.x;
            At[sc + 1][r] = a4.y;
            At[sc + 2][r] = a4.z;
            At[sc + 3][r] = a4.w;
        }
        __syncthreads();

        const float* Wp = &W[(size_t)h0 * ND + 8 * tc];
        #pragma unroll 4
        for (int kk = 0; kk < 64; ++kk) {
            float2 a2 = *(const float2*)&At[kk][2 * tr];
            float4 w0 = *(const float4*)&Wp[kk * ND];
            float4 w1 = *(const float4*)&Wp[kk * ND + 4];
            float wv[8] = {w0.x, w0.y, w0.z, w0.w, w1.x, w1.y, w1.z, w1.w};
            #pragma unroll
            for (int j = 0; j < 8; ++j) {
                acc0[j] += a2.x * wv[j];
                acc1[j] += a2.y * wv[j];
            }
        }
        __syncthreads();
    }

    float bsv[8];
    #pragma unroll
    for (int j = 0; j < 8; ++j) bsv[j] = bias[8 * tc + j];

    #pragma unroll
    for (int i = 0; i < 2; ++i) {
        float* accp = (i == 0) ? acc0 : acc1;
        int r = r0 + 2 * tr + i;
        float4 o0, o1;
        o0.x = accp[0] + bsv[0]; o0.y = accp[1] + bsv[1];
        o0.z = accp[2] + bsv[2]; o0.w = accp[3] + bsv[3];
        o1.x = accp[4] + bsv[4]; o1.y = accp[5] + bsv[5];
        o1.z = accp[6] + bsv[6]; o1.w = accp[7] + bsv[7];
        *(float4*)&dst[(size_t)r * ND + 8 * tc]     = o0;
        *(float4*)&dst[(size_t)r * ND + 8 * tc + 4] = o1;
    }
}

// ---------------------------------------------------------------------------
// Fused attention: one WG per pair of q rows, all 8 batches.
// grid 512, block 256.
// ---------------------------------------------------------------------------
__global__ __launch_bounds__(256, 2) void attn_kernel(
    const float* __restrict__ ws,
    const float* __restrict__ kbias, const float* __restrict__ vbias,
    const int* __restrict__ mask,
    float* __restrict__ out)
{
    __shared__ unsigned short w_lds[16][1032];  // row = qt*8+b; bf16 scores/weights
    __shared__ float q_lds[2][8][64];
    __shared__ float inv_l[16];

    const float* qp = ws;
    const float* kp = ws + NB * NS * ND;
    const float* vp = ws + 2 * NB * NS * ND;

    const int q0 = blockIdx.x * 2;
    const int t  = threadIdx.x;

    // ---- load q rows (scaled by 1/sqrt(D) = 1/8) ----
    {
        int rq = t >> 4;            // 0..15
        int qt = rq >> 3, b = rq & 7;
        int c  = (t & 15) * 4;
        float4 v = *(const float4*)&qp[((size_t)b * NS + q0 + qt) * ND + c];
        v.x *= 0.125f; v.y *= 0.125f; v.z *= 0.125f; v.w *= 0.125f;
        *(float4*)&q_lds[qt][b][c] = v;
    }
    __syncthreads();

    // ---- pass 1: scores s[qt][b][k] = q . (k + kbias), both qt per thread ----
    {
        const int b  = t >> 5;      // 0..7
        const int kl = t & 31;      // 0..31
        const float* kpb = kp + (size_t)b * NS * ND;
        const float* kbq0 = kbias + (size_t)q0 * NS * ND;
        const float* kbq1 = kbias + (size_t)(q0 + 1) * NS * ND;
        const int* mb = mask + b * NS;

        for (int jb = 0; jb < 8; ++jb) {
            float s0[4] = {0.f, 0.f, 0.f, 0.f};
            float s1[4] = {0.f, 0.f, 0.f, 0.f};
            #pragma unroll
            for (int dc = 0; dc < 4; ++dc) {
                float qf0[16], qf1[16];
                #pragma unroll
                for (int i = 0; i < 4; ++i) {
                    *(float4*)&qf0[4 * i] = *(const float4*)&q_lds[0][b][dc * 16 + 4 * i];
                    *(float4*)&qf1[4 * i] = *(const float4*)&q_lds[1][b][dc * 16 + 4 * i];
                }
                #pragma unroll
                for (int ks = 0; ks < 4; ++ks) {
                    const int k = kl + 32 * (4 * jb + ks);
                    const float* kvp = &kpb[(size_t)k * ND + dc * 16];
                    const float* p0  = &kbq0[(size_t)k * ND + dc * 16];
                    const float* p1  = &kbq1[(size_t)k * ND + dc * 16];
                    #pragma unroll
                    for (int i = 0; i < 4; ++i) {
                        const float4 kv = *(const float4*)(kvp + 4 * i);
                        const float4 c0 = *(const float4*)(p0 + 4 * i);
                        const float4 c1 = *(const float4*)(p1 + 4 * i);
                        s0[ks] += qf0[4*i+0] * (kv.x + c0.x) + qf0[4*i+1] * (kv.y + c0.y)
                                + qf0[4*i+2] * (kv.z + c0.z) + qf0[4*i+3] * (kv.w + c0.w);
                        s1[ks] += qf1[4*i+0] * (kv.x + c1.x) + qf1[4*i+1] * (kv.y + c1.y)
                                + qf1[4*i+2] * (kv.z + c1.z) + qf1[4*i+3] * (kv.w + c1.w);
                    }
                }
            }
            #pragma unroll
            for (int ks = 0; ks < 4; ++ks) {
                const int k = kl + 32 * (4 * jb + ks);
                float sa = s0[ks], sb = s1[ks];
                if (mb[k] == 0) { sa = -1e9f; sb = -1e9f; }
                w_lds[b][k]     = f2bf(sa);
                w_lds[8 + b][k] = f2bf(sb);
            }
        }
    }
    __syncthreads();

    // ---- softmax over k for each of 16 rows ----
    {
        const int row = t >> 4;     // 0..15
        const int idx = t & 15;     // 0..15
        const float LOG2E = 1.4426950408889634f;

        float m = -3.0e38f;
        #pragma unroll 4
        for (int i = 0; i < 32; ++i) {
            unsigned int pr = *(const unsigned int*)&w_lds[row][2 * idx + 32 * i];
            m = fmaxf(m, fmaxf(bflo(pr), bfhi(pr)));
        }
        #pragma unroll
        for (int off = 1; off < 16; off <<= 1) m = fmaxf(m, __shfl_xor(m, off, 64));

        float lsum = 0.f;
        #pragma unroll 4
        for (int i = 0; i < 32; ++i) {
            unsigned int pr = *(const unsigned int*)&w_lds[row][2 * idx + 32 * i];
            float e0 = exp2f((bflo(pr) - m) * LOG2E);
            float e1 = exp2f((bfhi(pr) - m) * LOG2E);
            lsum += e0 + e1;
            unsigned int packed = ((unsigned int)f2bf(e1) << 16) | (unsigned int)f2bf(e0);
            *(unsigned int*)&w_lds[row][2 * idx + 32 * i] = packed;
        }
        #pragma unroll
        for (int off = 1; off < 16; off <<= 1) lsum += __shfl_xor(lsum, off, 64);
        if (idx == 0) inv_l[row] = 1.0f / lsum;
    }
    __syncthreads();

    // ---- pass 2: out[b][q0+qt][:] = (1/l) * sum_k w * (v + vbias) ----
    {
        const int qt = t >> 7;          // 0..1
        const int b  = (t >> 4) & 7;    // 0..7
        const int dq = t & 15;          // 0..15 -> d = 4dq..4dq+3
        const float* vpb = vp + (size_t)b * NS * ND;
        const float* vbq = vbias + (size_t)(q0 + qt) * NS * ND;
        const unsigned short* wrow = &w_lds[qt * 8 + b][0];

        float ax = 0.f, ay = 0.f, az = 0.f, aw = 0.f;
        for (int k8 = 0; k8 < 128; ++k8) {
            uint4 wv = *(const uint4*)&wrow[8 * k8];
            float wk[8];
            wk[0] = bflo(wv.x); wk[1] = bfhi(wv.x);
            wk[2] = bflo(wv.y); wk[3] = bfhi(wv.y);
            wk[4] = bflo(wv.z); wk[5] = bfhi(wv.z);
            wk[6] = bflo(wv.w); wk[7] = bfhi(wv.w);
            #pragma unroll
            for (int i = 0; i < 8; ++i) {
                const int k = 8 * k8 + i;
                float4 v4  = *(const float4*)&vpb[(size_t)k * ND + 4 * dq];
                float4 vb4 = *(const float4*)&vbq[(size_t)k * ND + 4 * dq];
                ax += wk[i] * (v4.x + vb4.x);
                ay += wk[i] * (v4.y + vb4.y);
                az += wk[i] * (v4.z + vb4.z);
                aw += wk[i] * (v4.w + vb4.w);
            }
        }
        const float il = inv_l[qt * 8 + b];
        float4 o;
        o.x = ax * il; o.y = ay * il; o.z = az * il; o.w = aw * il;
        *(float4*)&out[((size_t)b * NS + q0 + qt) * ND + 4 * dq] = o;
    }
}

extern "C" void kernel_launch(void* const* d_in, const int* in_sizes, int n_in,
                              void* d_out, int out_size, void* d_ws, size_t ws_size,
                              hipStream_t stream) {
    (void)in_sizes; (void)n_in; (void)out_size; (void)ws_size;
    const float* query = (const float*)d_in[0];
    const float* key   = (const float*)d_in[1];
    const float* value = (const float*)d_in[2];
    const float* Wq    = (const float*)d_in[3];
    const float* bq    = (const float*)d_in[4];
    const float* Wk    = (const float*)d_in[5];
    const float* bk    = (const float*)d_in[6];
    const float* Wv    = (const float*)d_in[7];
    const float* bv    = (const float*)d_in[8];
    const float* kbias = (const float*)d_in[9];
    const float* vbias = (const float*)d_in[10];
    const int*   mask  = (const int*)d_in[11];
    float* ws  = (float*)d_ws;
    float* out = (float*)d_out;

    dim3 gp(128, 3), bp(256);
    proj_kernel<<<gp, bp, 0, stream>>>(query, key, value, Wq, bq, Wk, bk, Wv, bv, ws);
    attn_kernel<<<NS / 2, 256, 0, stream>>>(ws, kbias, vbias, mask, out);
}

// Round 2
// 451.554 us; speedup vs baseline: 1.5043x; 1.5043x over previous
//
#include <hip/hip_runtime.h>
#include <cstdint>
#include <cstddef>

#define NB 8
#define NS 1024
#define NH 1024
#define ND 64

__device__ __forceinline__ unsigned short f2bf(float x) {
    unsigned int u = __float_as_uint(x);
    return (unsigned short)((u + 0x7fffu + ((u >> 16) & 1u)) >> 16);
}
__device__ __forceinline__ float bf2f(unsigned short h) {
    return __uint_as_float(((unsigned int)h) << 16);
}

// ---------------------------------------------------------------------------
// Projection: dst[p] = A @ W + bias. A:[8192,1024], W:[1024,64].
// grid (256, 3), block 256. 32-row tile, per-thread 1 row x 8 cols.
// ---------------------------------------------------------------------------
__global__ __launch_bounds__(256, 3) void proj_kernel(
    const float* __restrict__ qin, const float* __restrict__ kin, const float* __restrict__ vin,
    const float* __restrict__ Wq, const float* __restrict__ bq,
    const float* __restrict__ Wk, const float* __restrict__ bk,
    const float* __restrict__ Wv, const float* __restrict__ bv,
    float* __restrict__ ws)
{
    __shared__ float As[32][65];

    const int p = blockIdx.y;
    const float* A    = (p == 0) ? qin : (p == 1) ? kin : vin;
    const float* W    = (p == 0) ? Wq  : (p == 1) ? Wk  : Wv;
    const float* bias = (p == 0) ? bq  : (p == 1) ? bk  : bv;
    float* dst = ws + (size_t)p * (NB * NS * ND);

    const int t  = threadIdx.x;
    const int r0 = blockIdx.x * 32;
    const int tr = t >> 3;          // 0..31 row within tile
    const int tc = t & 7;           // 0..7  col group (8 cols)
    const int lr = t >> 4;          // 0..15 staging row
    const int lc = (t & 15) * 4;    // staging col

    float acc[8];
    #pragma unroll
    for (int j = 0; j < 8; ++j) acc[j] = 0.f;

    for (int h0 = 0; h0 < NH; h0 += 64) {
        float4 a0 = *(const float4*)&A[(size_t)(r0 + lr) * NH + h0 + lc];
        float4 a1 = *(const float4*)&A[(size_t)(r0 + lr + 16) * NH + h0 + lc];
        __syncthreads();
        *(float4*)&As[lr][lc]      = a0;
        *(float4*)&As[lr + 16][lc] = a1;
        __syncthreads();

        const float* Wp = W + (size_t)h0 * ND + 8 * tc;
        #pragma unroll 4
        for (int kk = 0; kk < 64; ++kk) {
            float a  = As[tr][kk];
            float4 w0 = *(const float4*)&Wp[kk * ND];
            float4 w1 = *(const float4*)&Wp[kk * ND + 4];
            acc[0] += a * w0.x; acc[1] += a * w0.y;
            acc[2] += a * w0.z; acc[3] += a * w0.w;
            acc[4] += a * w1.x; acc[5] += a * w1.y;
            acc[6] += a * w1.z; acc[7] += a * w1.w;
        }
    }

    float4 o0, o1;
    o0.x = acc[0] + bias[8 * tc + 0]; o0.y = acc[1] + bias[8 * tc + 1];
    o0.z = acc[2] + bias[8 * tc + 2]; o0.w = acc[3] + bias[8 * tc + 3];
    o1.x = acc[4] + bias[8 * tc + 4]; o1.y = acc[5] + bias[8 * tc + 5];
    o1.z = acc[6] + bias[8 * tc + 6]; o1.w = acc[7] + bias[8 * tc + 7];
    *(float4*)&dst[(size_t)(r0 + tr) * ND + 8 * tc]     = o0;
    *(float4*)&dst[(size_t)(r0 + tr) * ND + 8 * tc + 4] = o1;
}

// ---------------------------------------------------------------------------
// Fused attention: one WG per q row. grid 1024, block 256 (4 waves).
// Lane layout per wave: kr = lane>>4 (4 k-rows), dq = lane&15 (d quad).
// ---------------------------------------------------------------------------
__global__ __launch_bounds__(256, 4) void attn_kernel(
    const float* __restrict__ ws,
    const float* __restrict__ kbias, const float* __restrict__ vbias,
    const int* __restrict__ mask,
    float* __restrict__ out)
{
    __shared__ unsigned short w_lds[NS][8];   // [k][b] bf16 scores/weights, 16 KB
    __shared__ float red[4][8][64];           // cross-wave reduce, 8 KB

    const float* qp = ws;
    const float* kp = ws + NB * NS * ND;
    const float* vp = ws + 2 * NB * NS * ND;

    const int qr = blockIdx.x;
    const int t  = threadIdx.x;
    const int wv = t >> 6;          // wave 0..3
    const int l  = t & 63;
    const int kr = l >> 4;          // 0..3 k-row within wave-iter
    const int dq = l & 15;          // 0..15 d-quad

    // ---- hoist q into registers (scaled by 1/sqrt(D) = 1/8) ----
    float4 qv[8];
    #pragma unroll
    for (int b = 0; b < 8; ++b) {
        float4 v = *(const float4*)&qp[((size_t)b * NS + qr) * ND + 4 * dq];
        v.x *= 0.125f; v.y *= 0.125f; v.z *= 0.125f; v.w *= 0.125f;
        qv[b] = v;
    }

    const float* kbq = kbias + (size_t)qr * NS * ND;
    const float* vbq = vbias + (size_t)qr * NS * ND;

    // ---- pass 1: scores s[b][k] = q_b . (k_b + kbias) ----
    for (int jj = 0; jj < 64; ++jj) {
        const int k = jj * 16 + wv * 4 + kr;
        const float4 c = *(const float4*)&kbq[(size_t)k * ND + 4 * dq];

        float s[8];
        #pragma unroll
        for (int b = 0; b < 8; ++b) {
            const float4 kv = *(const float4*)&kp[((size_t)b * NS + k) * ND + 4 * dq];
            float tx = kv.x + c.x, ty = kv.y + c.y, tz = kv.z + c.z, tw = kv.w + c.w;
            s[b] = qv[b].x * tx + qv[b].y * ty + qv[b].z * tz + qv[b].w * tw;
        }
        #pragma unroll
        for (int b = 0; b < 8; ++b) {
            s[b] += __shfl_xor(s[b], 1, 16);
            s[b] += __shfl_xor(s[b], 2, 16);
            s[b] += __shfl_xor(s[b], 4, 16);
            s[b] += __shfl_xor(s[b], 8, 16);
        }
        if (dq < 8) {
            float sv = s[0];
            #pragma unroll
            for (int b = 1; b < 8; ++b) sv = (dq == b) ? s[b] : sv;
            w_lds[k][dq] = f2bf(sv);
        }
    }
    __syncthreads();

    // ---- softmax per (b) row; mask applied here; weights normalized ----
    {
        const int row = t >> 5;     // 0..7 = b
        const int idx = t & 31;     // 0..31
        const int* mb = mask + row * NS;
        const float LOG2E = 1.4426950408889634f;

        float sv[32];
        float m = -3.0e38f;
        #pragma unroll
        for (int i = 0; i < 32; ++i) {
            const int k = idx + 32 * i;
            float x = bf2f(w_lds[k][row]);
            if (mb[k] == 0) x = -1e9f;
            sv[i] = x;
            m = fmaxf(m, x);
        }
        #pragma unroll
        for (int off = 1; off < 32; off <<= 1) m = fmaxf(m, __shfl_xor(m, off, 32));

        float lsum = 0.f;
        #pragma unroll
        for (int i = 0; i < 32; ++i) {
            sv[i] = exp2f((sv[i] - m) * LOG2E);
            lsum += sv[i];
        }
        #pragma unroll
        for (int off = 1; off < 32; off <<= 1) lsum += __shfl_xor(lsum, off, 32);
        const float il = 1.0f / lsum;

        #pragma unroll
        for (int i = 0; i < 32; ++i) {
            const int k = idx + 32 * i;
            w_lds[k][row] = f2bf(sv[i] * il);
        }
    }
    __syncthreads();

    // ---- pass 2: out[b][:] = sum_k w[b,k] * (v_b[k,:] + vbias[q,k,:]) ----
    float4 acc[8];
    #pragma unroll
    for (int b = 0; b < 8; ++b) { acc[b].x = 0.f; acc[b].y = 0.f; acc[b].z = 0.f; acc[b].w = 0.f; }

    for (int jj = 0; jj < 64; ++jj) {
        const int k = jj * 16 + wv * 4 + kr;
        const float4 cb = *(const float4*)&vbq[(size_t)k * ND + 4 * dq];
        #pragma unroll
        for (int b = 0; b < 8; ++b) {
            const float w = bf2f(w_lds[k][b]);
            const float4 vv = *(const float4*)&vp[((size_t)b * NS + k) * ND + 4 * dq];
            acc[b].x += w * (vv.x + cb.x);
            acc[b].y += w * (vv.y + cb.y);
            acc[b].z += w * (vv.z + cb.z);
            acc[b].w += w * (vv.w + cb.w);
        }
    }

    // intra-wave reduce over kr (lanes +-16, +-32)
    #pragma unroll
    for (int b = 0; b < 8; ++b) {
        #pragma unroll
        for (int off = 16; off <= 32; off <<= 1) {
            acc[b].x += __shfl_xor(acc[b].x, off, 64);
            acc[b].y += __shfl_xor(acc[b].y, off, 64);
            acc[b].z += __shfl_xor(acc[b].z, off, 64);
            acc[b].w += __shfl_xor(acc[b].w, off, 64);
        }
    }
    if (l < 16) {
        #pragma unroll
        for (int b = 0; b < 8; ++b) *(float4*)&red[wv][b][4 * dq] = acc[b];
    }
    __syncthreads();

    if (t < 128) {
        const int b = t >> 4, d = (t & 15) * 4;
        float4 r0 = *(float4*)&red[0][b][d];
        float4 r1 = *(float4*)&red[1][b][d];
        float4 r2 = *(float4*)&red[2][b][d];
        float4 r3 = *(float4*)&red[3][b][d];
        float4 o;
        o.x = r0.x + r1.x + r2.x + r3.x;
        o.y = r0.y + r1.y + r2.y + r3.y;
        o.z = r0.z + r1.z + r2.z + r3.z;
        o.w = r0.w + r1.w + r2.w + r3.w;
        *(float4*)&out[((size_t)b * NS + qr) * ND + d] = o;
    }
}

extern "C" void kernel_launch(void* const* d_in, const int* in_sizes, int n_in,
                              void* d_out, int out_size, void* d_ws, size_t ws_size,
                              hipStream_t stream) {
    (void)in_sizes; (void)n_in; (void)out_size; (void)ws_size;
    const float* query = (const float*)d_in[0];
    const float* key   = (const float*)d_in[1];
    const float* value = (const float*)d_in[2];
    const float* Wq    = (const float*)d_in[3];
    const float* bq    = (const float*)d_in[4];
    const float* Wk    = (const float*)d_in[5];
    const float* bk    = (const float*)d_in[6];
    const float* Wv    = (const float*)d_in[7];
    const float* bv    = (const float*)d_in[8];
    const float* kbias = (const float*)d_in[9];
    const float* vbias = (const float*)d_in[10];
    const int*   mask  = (const int*)d_in[11];
    float* ws  = (float*)d_ws;
    float* out = (float*)d_out;

    dim3 gp(256, 3), bp(256);
    proj_kernel<<<gp, bp, 0, stream>>>(query, key, value, Wq, bq, Wk, bk, Wv, bv, ws);
    attn_kernel<<<NS, 256, 0, stream>>>(ws, kbias, vbias, mask, out);
}